// Round 5
// baseline (1733.891 us; speedup 1.0000x reference)
//
#include <hip/hip_runtime.h>

// ---------------------------------------------------------------------------
// LowFreqSparseAttention: qkv 1x1conv -> l2norm(q,k) -> S=QK^T*scale ->
// top-k(k=N/2) mask -> softmax -> PV -> proj 1x1conv -> GroupNorm(32 groups).
// B=1, C=256, H=W=64 -> N=4096, 8 heads, hd=32, k_sel=2048.
//
// R5 (post-mortem R4: VGPR_Count=60 proves kr[64] went to SCRATCH -- the
// phase-2 chunk loop wasn't unrolled, so kr was dynamically indexed and
// LLVM demoted it to private memory; 528MB write + 502MB fetch = the spill).
// Fix: #pragma unroll on the phase-2 loop. Every loop touching kr is now
// fully unrolled -> all indices constant -> kr register-resident.
// Numerics identical to R4.
// ---------------------------------------------------------------------------

#define NTOK 4096
#define HD 32
#define NHEADS 8
#define KSEL 2048
#define SCALE 0.17677669529663689f   // 32^-0.5  (folded into l2norm_q)

// ---- helpers --------------------------------------------------------------

__device__ __forceinline__ unsigned fkey(float f) {
  // monotonic map fp32 -> uint (ascending)
  unsigned b = __float_as_uint(f);
  return (b & 0x80000000u) ? ~b : (b | 0x80000000u);
}
__device__ __forceinline__ float unfkey(unsigned k) {
  unsigned b = (k & 0x80000000u) ? (k ^ 0x80000000u) : ~k;
  return __uint_as_float(b);
}
__device__ __forceinline__ unsigned short f2bf(float f) {  // RTNE
  unsigned u = __float_as_uint(f);
  u += 0x7FFFu + ((u >> 16) & 1u);
  return (unsigned short)(u >> 16);
}
__device__ __forceinline__ float bf2f(unsigned short b) {
  return __uint_as_float(((unsigned)b) << 16);
}

// ---- kernel 1/4: GEMM  C[M][4096] = A[M][256] * B[256][4096] --------------
// SCATTER: M=768 -> Q [h][n][d], KT [h][d][n] (transposed!), V [h][n][d].
// else:    M=256 -> plain row-major C0.

template <bool SCATTER>
__global__ __launch_bounds__(256) void gemm_k256(
    const float* __restrict__ A, const float* __restrict__ B,
    float* __restrict__ C0, float* __restrict__ C1, float* __restrict__ C2) {
  __shared__ float Wt[64][17];   // +1 pad: avoid 16-way bank conflict
  __shared__ float Xt[16][64];

  const int tid = threadIdx.x;
  const int tx = tid & 15, ty = tid >> 4;
  const int o0 = blockIdx.y * 64, n0 = blockIdx.x * 64;

  const int wr = tid >> 2, wc = (tid & 3) << 2;   // W-tile 64x16 loader
  const int xr = tid >> 4, xc = (tid & 15) << 2;  // X-tile 16x64 loader

  float4 acc[4];
#pragma unroll
  for (int i = 0; i < 4; ++i) acc[i] = make_float4(0.f, 0.f, 0.f, 0.f);

  for (int k0 = 0; k0 < 256; k0 += 16) {
    float4 wv = *(const float4*)(A + (o0 + wr) * 256 + k0 + wc);
    float4 xv = *(const float4*)(B + (k0 + xr) * 4096 + n0 + xc);
    Wt[wr][wc + 0] = wv.x; Wt[wr][wc + 1] = wv.y;
    Wt[wr][wc + 2] = wv.z; Wt[wr][wc + 3] = wv.w;
    *(float4*)&Xt[xr][xc] = xv;
    __syncthreads();
#pragma unroll
    for (int kk = 0; kk < 16; ++kk) {
      float4 b = *(const float4*)&Xt[kk][tx << 2];
#pragma unroll
      for (int i = 0; i < 4; ++i) {
        float a = Wt[(ty << 2) + i][kk];
        acc[i].x += a * b.x; acc[i].y += a * b.y;
        acc[i].z += a * b.z; acc[i].w += a * b.w;
      }
    }
    __syncthreads();
  }

  if (SCATTER) {
#pragma unroll
    for (int i = 0; i < 4; ++i) {
      int o = o0 + (ty << 2) + i;
      int which = o >> 8, rem = o & 255;
      int h = rem >> 5, d = rem & 31;
      int n = n0 + (tx << 2);
      if (which == 1) {
        // KT[h][d][n..n+3]: contiguous float4
        *(float4*)(C1 + h * (HD * NTOK) + d * NTOK + n) = acc[i];
      } else {
        float* dst = (which == 0) ? C0 : C2;
        int base = h * (NTOK * HD) + d;
        dst[base + (n + 0) * HD] = acc[i].x;
        dst[base + (n + 1) * HD] = acc[i].y;
        dst[base + (n + 2) * HD] = acc[i].z;
        dst[base + (n + 3) * HD] = acc[i].w;
      }
    }
  } else {
#pragma unroll
    for (int i = 0; i < 4; ++i) {
      int o = o0 + (ty << 2) + i;
      *(float4*)(C0 + o * 4096 + n0 + (tx << 2)) = acc[i];
    }
  }
}

// ---- kernel 2a: l2norm Q rows [h][n][32], folds SCALE ---------------------

__global__ __launch_bounds__(256) void l2norm_q(float* __restrict__ Q) {
  const int tid = threadIdx.x;
  const int p = blockIdx.x * 8 + (tid >> 5);  // (head*4096+n) row index
  const int d = tid & 31;
  const int idx = p * HD + d;
  float v = Q[idx];
  float ss = v * v;
#pragma unroll
  for (int m = 16; m >= 1; m >>= 1) ss += __shfl_xor(ss, m, 32);
  float nrm = sqrtf(ss);
  Q[idx] = v * SCALE / fmaxf(nrm, 1e-12f);
}

// ---- kernel 2b: l2norm KT columns (norm over d at fixed n) ----------------

__global__ __launch_bounds__(256) void l2norm_kt(float* __restrict__ KT) {
  const int n = blockIdx.x * 256 + threadIdx.x;
  float* P = KT + blockIdx.y * (HD * NTOK) + n;
  float v[HD];
  float ss = 0.f;
#pragma unroll
  for (int d = 0; d < HD; ++d) {
    v[d] = P[d * NTOK];          // coalesced across lanes
    ss += v[d] * v[d];
  }
  float inv = 1.f / fmaxf(sqrtf(ss), 1e-12f);
#pragma unroll
  for (int d = 0; d < HD; ++d) P[d * NTOK] = v[d] * inv;
}

// ---- kernel 3: fused attention (4 rows per block, wave wv owns row wv) ----
// phase2: wave-per-row scores from KT, dwordx4-coalesced, keys -> kr[64]
//         (FULLY UNROLLED: kr must stay register-resident)
// phase3: exact 32-iter ballot-bisection for the 2048th-largest key
// phase4: weights = kept ? bf16(exp(s)) : 0 -> wtsP[row][m] (b64 writes)
// phase5: PV accumulate (V fp32), cross-lane reduce, write AO[c][n]

__global__ __launch_bounds__(256) void attn_kernel(
    const float* __restrict__ Q, const float* __restrict__ KT,
    const float* __restrict__ V, float* __restrict__ AO) {
  __shared__ __align__(16) unsigned short wtsP[4][NTOK];  // 32 KB, [row][m]
  __shared__ float qs[128];
  __shared__ float pvred[4 * 8 * 4 * 4];                  // 2 KB
  __shared__ float redf[4];

  const int tid = threadIdx.x;
  const int wv = tid >> 6, lane = tid & 63;
  const int head = blockIdx.x & 7;          // head == blockIdx%8 -> XCD-pinned
  const int n0 = (blockIdx.x >> 3) << 2;

  const float* Qh = Q + head * (NTOK * HD);
  const float* KTh = KT + head * (HD * NTOK);
  const float* Vh = V + head * (NTOK * HD);

  // phase 1: stage the block's 4 q rows (already *SCALE from l2norm_q)
  if (tid < 128) qs[tid] = Qh[n0 * HD + tid];
  __syncthreads();

  float qv[HD];
#pragma unroll
  for (int d = 0; d < HD; ++d) qv[d] = qs[wv * HD + d];

  // phase 2: wave wv computes row wv's scores. Chunk = 256 columns; lane
  // handles 4 consecutive columns via dwordx4 along n. kr[ch*4+t] holds
  // column ch*256 + lane*4 + t. FULL unroll: every kr index is a constant
  // (dynamic indexing demotes kr to scratch -- that was R4's 1 GB of
  // spill traffic). Per-chunk barrier keeps waves in-step / chunk L1-hot.
  unsigned kr[64];
  const int cbase = lane << 2;
#pragma unroll
  for (int ch = 0; ch < 16; ++ch) {
    const float* kp = KTh + (ch << 8) + cbase;
    float a0 = 0.f, a1 = 0.f, a2 = 0.f, a3 = 0.f;
#pragma unroll
    for (int d = 0; d < HD; ++d) {
      float4 kv = *(const float4*)(kp + d * NTOK);
      a0 += qv[d] * kv.x; a1 += qv[d] * kv.y;
      a2 += qv[d] * kv.z; a3 += qv[d] * kv.w;
    }
    kr[(ch << 2) + 0] = fkey(a0);
    kr[(ch << 2) + 1] = fkey(a1);
    kr[(ch << 2) + 2] = fkey(a2);
    kr[(ch << 2) + 3] = fkey(a3);
    __syncthreads();
  }

  // phase 3: exact bisection, t = max{T : count(key >= T) >= KSEL}.
  unsigned lo = 0u, hi = 0xFFFFFFFFu;
  for (int it = 0; it < 32; ++it) {
    unsigned mid = (unsigned)((((unsigned long long)lo) + hi + 1ull) >> 1);
    int c = 0;
#pragma unroll
    for (int i = 0; i < 64; ++i)
      c += __popcll(__ballot(kr[i] >= mid));
    if (c >= KSEL) lo = mid; else hi = mid - 1;
  }
  const unsigned tkey = lo;

  // phase 4: weights + denominator for row wv. kr[g*4+t] -> m = g*256+lane*4+t
  float denom = 0.f;
#pragma unroll
  for (int g = 0; g < 16; ++g) {
    const int mb = (g << 8) + cbase;
    ushort4 wb;
    unsigned short* pw = (unsigned short*)&wb;
#pragma unroll
    for (int t = 0; t < 4; ++t) {
      unsigned kk = kr[(g << 2) + t];
      float w = 0.f;
      unsigned short b = 0;
      if (kk >= tkey) {
        w = __expf(unfkey(kk));
        b = f2bf(w);
        w = bf2f(b);  // denom consistent with bf16 numerator
      }
      pw[t] = b;
      denom += w;
    }
    *(ushort4*)&wtsP[wv][mb] = wb;  // 8-B aligned (mb % 4 == 0)
  }
#pragma unroll
  for (int s = 1; s < 64; s <<= 1) denom += __shfl_xor(denom, s);
  if (lane == 0) redf[wv] = denom;
  __syncthreads();  // wtsP + redf visible to all

  // phase 5: PV. wave wv covers m in [wv*1024, wv*1024+1024)
  const int slot = lane & 7, mg = lane >> 3;
  const int mbase = wv << 10;
  float av[4][4];
#pragma unroll
  for (int r = 0; r < 4; ++r)
#pragma unroll
    for (int c = 0; c < 4; ++c) av[r][c] = 0.f;

#pragma unroll 4
  for (int ii = 0; ii < 128; ++ii) {
    const int m = mbase + (ii << 3) + mg;
    float w0 = bf2f(wtsP[0][m]);
    float w1 = bf2f(wtsP[1][m]);
    float w2 = bf2f(wtsP[2][m]);
    float w3 = bf2f(wtsP[3][m]);
    float4 v = *(const float4*)(Vh + m * HD + (slot << 2));
    av[0][0] += w0 * v.x; av[0][1] += w0 * v.y; av[0][2] += w0 * v.z; av[0][3] += w0 * v.w;
    av[1][0] += w1 * v.x; av[1][1] += w1 * v.y; av[1][2] += w1 * v.z; av[1][3] += w1 * v.w;
    av[2][0] += w2 * v.x; av[2][1] += w2 * v.y; av[2][2] += w2 * v.z; av[2][3] += w2 * v.w;
    av[3][0] += w3 * v.x; av[3][1] += w3 * v.y; av[3][2] += w3 * v.z; av[3][3] += w3 * v.w;
  }
  // reduce over mg (lane bits 3..5)
#pragma unroll
  for (int r = 0; r < 4; ++r)
#pragma unroll
    for (int c = 0; c < 4; ++c) {
      float x = av[r][c];
      x += __shfl_xor(x, 8); x += __shfl_xor(x, 16); x += __shfl_xor(x, 32);
      av[r][c] = x;
    }
  if (mg == 0) {
#pragma unroll
    for (int r = 0; r < 4; ++r)
#pragma unroll
      for (int c = 0; c < 4; ++c)
        pvred[(((wv << 3) + slot) * 4 + r) * 4 + c] = av[r][c];
  }
  __syncthreads();

  if (tid < 128) {
    const int r = tid >> 5, d = tid & 31;
    const int sl = d >> 2, c = d & 3;
    float val = 0.f;
#pragma unroll
    for (int w = 0; w < 4; ++w) val += pvred[(((w << 3) + sl) * 4 + r) * 4 + c];
    val /= redf[r];
    AO[(head * HD + d) * NTOK + n0 + r] = val;  // [C][N] for proj GEMM
  }
}

// ---- kernel 5: GroupNorm stats (32 groups of 8 ch x 4096 = 32768 vals) ----

__global__ __launch_bounds__(256) void gn_stats(const float* __restrict__ O,
                                                float* __restrict__ ST) {
  const int g = blockIdx.x, tid = threadIdx.x;
  const float4* p4 = (const float4*)(O + g * 32768);
  float s = 0.f, ss = 0.f;
  for (int i = tid; i < 8192; i += 256) {
    float4 v = p4[i];
    s += (v.x + v.y) + (v.z + v.w);
    ss += (v.x * v.x + v.y * v.y) + (v.z * v.z + v.w * v.w);
  }
#pragma unroll
  for (int m = 1; m < 64; m <<= 1) {
    s += __shfl_xor(s, m);
    ss += __shfl_xor(ss, m);
  }
  __shared__ float rs[4], rss[4];
  if ((tid & 63) == 0) { rs[tid >> 6] = s; rss[tid >> 6] = ss; }
  __syncthreads();
  if (tid == 0) {
    float S = rs[0] + rs[1] + rs[2] + rs[3];
    float SS = rss[0] + rss[1] + rss[2] + rss[3];
    float mean = S * (1.f / 32768.f);
    float var = SS * (1.f / 32768.f) - mean * mean;
    ST[g * 2] = mean;
    ST[g * 2 + 1] = rsqrtf(var + 1e-6f);
  }
}

// ---- kernel 6: GroupNorm apply (in place on d_out) ------------------------
// Indexes FLOAT4s: total 1048576/4 = 262144 -> grid 1024 x 256.

__global__ __launch_bounds__(256) void gn_apply(float* __restrict__ O,
                                                const float* __restrict__ ST,
                                                const float* __restrict__ gamma,
                                                const float* __restrict__ beta) {
  const int i4 = blockIdx.x * 256 + threadIdx.x;  // float4 index
  const int c = i4 >> 10, g = c >> 3;
  const float a = ST[g * 2 + 1] * gamma[c];
  const float b = beta[c] - ST[g * 2] * a;
  float4 v = *(float4*)(O + (i4 << 2));
  v.x = v.x * a + b; v.y = v.y * a + b; v.z = v.z * a + b; v.w = v.w * a + b;
  *(float4*)(O + (i4 << 2)) = v;
}

// ---- launch ---------------------------------------------------------------

extern "C" void kernel_launch(void* const* d_in, const int* in_sizes, int n_in,
                              void* d_out, int out_size, void* d_ws,
                              size_t ws_size, hipStream_t stream) {
  const float* x = (const float*)d_in[0];       // [256][4096]
  const float* w_qkv = (const float*)d_in[1];   // [768][256]
  const float* w_proj = (const float*)d_in[2];  // [256][256]
  const float* gamma = (const float*)d_in[3];   // [256]
  const float* beta = (const float*)d_in[4];    // [256]
  float* out = (float*)d_out;                   // [256][4096]

  float* Q = (float*)d_ws;          // [8][4096][32]
  float* KT = Q + 1048576;          // [8][32][4096]  (transposed)
  float* V = KT + 1048576;          // [8][4096][32]
  float* AO = V + 1048576;          // [256][4096]
  float* ST = AO + 1048576;         // [32][2]

  gemm_k256<true><<<dim3(64, 12), 256, 0, stream>>>(w_qkv, x, Q, KT, V);
  l2norm_q<<<4096, 256, 0, stream>>>(Q);
  l2norm_kt<<<dim3(16, 8), 256, 0, stream>>>(KT);
  attn_kernel<<<8192, 256, 0, stream>>>(Q, KT, V, AO);
  gemm_k256<false><<<dim3(64, 4), 256, 0, stream>>>(w_proj, AO, out, nullptr, nullptr);
  gn_stats<<<32, 256, 0, stream>>>(out, ST);
  gn_apply<<<1024, 256, 0, stream>>>(out, ST, gamma, beta);
}

// Round 6
// 1170.689 us; speedup vs baseline: 1.4811x; 1.4811x over previous
//
#include <hip/hip_runtime.h>

// ---------------------------------------------------------------------------
// LowFreqSparseAttention: qkv 1x1conv -> l2norm(q,k) -> S=QK^T*scale ->
// top-k(k=N/2) mask -> softmax -> PV -> proj 1x1conv -> GroupNorm(32 groups).
// B=1, C=256, H=W=64 -> N=4096, 8 heads, hd=32, k_sel=2048.
//
// R6 (post-mortem R5: spill fixed -- VGPR 160, hbm 10MB -- but dur 1708us,
// VALUBusy 22%: latency-bound. The 16 per-chunk __syncthreads in phase 2
// forced a vmcnt-drain every 32 loads, defeating cross-chunk pipelining,
// with only 12 waves/CU to cover the stalls):
//  * phase 2 barriers REMOVED -- kr is private, no LDS hazard exists. The
//    unrolled loop now exposes 512 independent K loads for deep pipelining.
//    K/V stay L2-resident per XCD (head = blockIdx&7 pins head->XCD).
//  * phase 5 unroll widened 4 -> 8.
// Numerics bit-identical to R5 (absmax 0.015625 expected unchanged).
// ---------------------------------------------------------------------------

#define NTOK 4096
#define HD 32
#define NHEADS 8
#define KSEL 2048
#define SCALE 0.17677669529663689f   // 32^-0.5  (folded into l2norm_q)

// ---- helpers --------------------------------------------------------------

__device__ __forceinline__ unsigned fkey(float f) {
  // monotonic map fp32 -> uint (ascending)
  unsigned b = __float_as_uint(f);
  return (b & 0x80000000u) ? ~b : (b | 0x80000000u);
}
__device__ __forceinline__ float unfkey(unsigned k) {
  unsigned b = (k & 0x80000000u) ? (k ^ 0x80000000u) : ~k;
  return __uint_as_float(b);
}
__device__ __forceinline__ unsigned short f2bf(float f) {  // RTNE
  unsigned u = __float_as_uint(f);
  u += 0x7FFFu + ((u >> 16) & 1u);
  return (unsigned short)(u >> 16);
}
__device__ __forceinline__ float bf2f(unsigned short b) {
  return __uint_as_float(((unsigned)b) << 16);
}

// ---- kernel 1/4: GEMM  C[M][4096] = A[M][256] * B[256][4096] --------------
// SCATTER: M=768 -> Q [h][n][d], KT [h][d][n] (transposed!), V [h][n][d].
// else:    M=256 -> plain row-major C0.

template <bool SCATTER>
__global__ __launch_bounds__(256) void gemm_k256(
    const float* __restrict__ A, const float* __restrict__ B,
    float* __restrict__ C0, float* __restrict__ C1, float* __restrict__ C2) {
  __shared__ float Wt[64][17];   // +1 pad: avoid 16-way bank conflict
  __shared__ float Xt[16][64];

  const int tid = threadIdx.x;
  const int tx = tid & 15, ty = tid >> 4;
  const int o0 = blockIdx.y * 64, n0 = blockIdx.x * 64;

  const int wr = tid >> 2, wc = (tid & 3) << 2;   // W-tile 64x16 loader
  const int xr = tid >> 4, xc = (tid & 15) << 2;  // X-tile 16x64 loader

  float4 acc[4];
#pragma unroll
  for (int i = 0; i < 4; ++i) acc[i] = make_float4(0.f, 0.f, 0.f, 0.f);

  for (int k0 = 0; k0 < 256; k0 += 16) {
    float4 wv = *(const float4*)(A + (o0 + wr) * 256 + k0 + wc);
    float4 xv = *(const float4*)(B + (k0 + xr) * 4096 + n0 + xc);
    Wt[wr][wc + 0] = wv.x; Wt[wr][wc + 1] = wv.y;
    Wt[wr][wc + 2] = wv.z; Wt[wr][wc + 3] = wv.w;
    *(float4*)&Xt[xr][xc] = xv;
    __syncthreads();
#pragma unroll
    for (int kk = 0; kk < 16; ++kk) {
      float4 b = *(const float4*)&Xt[kk][tx << 2];
#pragma unroll
      for (int i = 0; i < 4; ++i) {
        float a = Wt[(ty << 2) + i][kk];
        acc[i].x += a * b.x; acc[i].y += a * b.y;
        acc[i].z += a * b.z; acc[i].w += a * b.w;
      }
    }
    __syncthreads();
  }

  if (SCATTER) {
#pragma unroll
    for (int i = 0; i < 4; ++i) {
      int o = o0 + (ty << 2) + i;
      int which = o >> 8, rem = o & 255;
      int h = rem >> 5, d = rem & 31;
      int n = n0 + (tx << 2);
      if (which == 1) {
        // KT[h][d][n..n+3]: contiguous float4
        *(float4*)(C1 + h * (HD * NTOK) + d * NTOK + n) = acc[i];
      } else {
        float* dst = (which == 0) ? C0 : C2;
        int base = h * (NTOK * HD) + d;
        dst[base + (n + 0) * HD] = acc[i].x;
        dst[base + (n + 1) * HD] = acc[i].y;
        dst[base + (n + 2) * HD] = acc[i].z;
        dst[base + (n + 3) * HD] = acc[i].w;
      }
    }
  } else {
#pragma unroll
    for (int i = 0; i < 4; ++i) {
      int o = o0 + (ty << 2) + i;
      *(float4*)(C0 + o * 4096 + n0 + (tx << 2)) = acc[i];
    }
  }
}

// ---- kernel 2a: l2norm Q rows [h][n][32], folds SCALE ---------------------

__global__ __launch_bounds__(256) void l2norm_q(float* __restrict__ Q) {
  const int tid = threadIdx.x;
  const int p = blockIdx.x * 8 + (tid >> 5);  // (head*4096+n) row index
  const int d = tid & 31;
  const int idx = p * HD + d;
  float v = Q[idx];
  float ss = v * v;
#pragma unroll
  for (int m = 16; m >= 1; m >>= 1) ss += __shfl_xor(ss, m, 32);
  float nrm = sqrtf(ss);
  Q[idx] = v * SCALE / fmaxf(nrm, 1e-12f);
}

// ---- kernel 2b: l2norm KT columns (norm over d at fixed n) ----------------

__global__ __launch_bounds__(256) void l2norm_kt(float* __restrict__ KT) {
  const int n = blockIdx.x * 256 + threadIdx.x;
  float* P = KT + blockIdx.y * (HD * NTOK) + n;
  float v[HD];
  float ss = 0.f;
#pragma unroll
  for (int d = 0; d < HD; ++d) {
    v[d] = P[d * NTOK];          // coalesced across lanes
    ss += v[d] * v[d];
  }
  float inv = 1.f / fmaxf(sqrtf(ss), 1e-12f);
#pragma unroll
  for (int d = 0; d < HD; ++d) P[d * NTOK] = v[d] * inv;
}

// ---- kernel 3: fused attention (4 rows per block, wave wv owns row wv) ----
// phase2: wave-per-row scores from KT, dwordx4-coalesced, keys -> kr[64]
//         (fully unrolled, NO barriers -> deep cross-chunk load pipelining)
// phase3: exact 32-iter ballot-bisection for the 2048th-largest key
// phase4: weights = kept ? bf16(exp(s)) : 0 -> wtsP[row][m]
// phase5: PV accumulate (V fp32), cross-lane reduce, write AO[c][n]

__global__ __launch_bounds__(256) void attn_kernel(
    const float* __restrict__ Q, const float* __restrict__ KT,
    const float* __restrict__ V, float* __restrict__ AO) {
  __shared__ __align__(16) unsigned short wtsP[4][NTOK];  // 32 KB, [row][m]
  __shared__ float qs[128];
  __shared__ float pvred[4 * 8 * 4 * 4];                  // 2 KB
  __shared__ float redf[4];

  const int tid = threadIdx.x;
  const int wv = tid >> 6, lane = tid & 63;
  const int head = blockIdx.x & 7;          // head == blockIdx%8 -> XCD-pinned
  const int n0 = (blockIdx.x >> 3) << 2;

  const float* Qh = Q + head * (NTOK * HD);
  const float* KTh = KT + head * (HD * NTOK);
  const float* Vh = V + head * (NTOK * HD);

  // phase 1: stage the block's 4 q rows (already *SCALE from l2norm_q)
  if (tid < 128) qs[tid] = Qh[n0 * HD + tid];
  __syncthreads();

  float qv[HD];
#pragma unroll
  for (int d = 0; d < HD; ++d) qv[d] = qs[wv * HD + d];

  // phase 2: wave wv computes row wv's scores. Chunk = 256 columns; lane
  // handles 4 consecutive columns via dwordx4 along n. kr[ch*4+t] holds
  // column ch*256 + lane*4 + t. FULL unroll keeps kr register-resident
  // (dynamic indexing demotes it to scratch -- R4's 1 GB spill). NO
  // barriers: kr is private, K/V are L2-resident per XCD; barriers here
  // only serialized the 512-load pipeline (R5's 22% VALUBusy).
  unsigned kr[64];
  const int cbase = lane << 2;
#pragma unroll
  for (int ch = 0; ch < 16; ++ch) {
    const float* kp = KTh + (ch << 8) + cbase;
    float a0 = 0.f, a1 = 0.f, a2 = 0.f, a3 = 0.f;
#pragma unroll
    for (int d = 0; d < HD; ++d) {
      float4 kv = *(const float4*)(kp + d * NTOK);
      a0 += qv[d] * kv.x; a1 += qv[d] * kv.y;
      a2 += qv[d] * kv.z; a3 += qv[d] * kv.w;
    }
    kr[(ch << 2) + 0] = fkey(a0);
    kr[(ch << 2) + 1] = fkey(a1);
    kr[(ch << 2) + 2] = fkey(a2);
    kr[(ch << 2) + 3] = fkey(a3);
  }

  // phase 3: exact bisection, t = max{T : count(key >= T) >= KSEL}.
  unsigned lo = 0u, hi = 0xFFFFFFFFu;
  for (int it = 0; it < 32; ++it) {
    unsigned mid = (unsigned)((((unsigned long long)lo) + hi + 1ull) >> 1);
    int c = 0;
#pragma unroll
    for (int i = 0; i < 64; ++i)
      c += __popcll(__ballot(kr[i] >= mid));
    if (c >= KSEL) lo = mid; else hi = mid - 1;
  }
  const unsigned tkey = lo;

  // phase 4: weights + denominator for row wv. kr[g*4+t] -> m = g*256+lane*4+t
  float denom = 0.f;
#pragma unroll
  for (int g = 0; g < 16; ++g) {
    const int mb = (g << 8) + cbase;
    ushort4 wb;
    unsigned short* pw = (unsigned short*)&wb;
#pragma unroll
    for (int t = 0; t < 4; ++t) {
      unsigned kk = kr[(g << 2) + t];
      float w = 0.f;
      unsigned short b = 0;
      if (kk >= tkey) {
        w = __expf(unfkey(kk));
        b = f2bf(w);
        w = bf2f(b);  // denom consistent with bf16 numerator
      }
      pw[t] = b;
      denom += w;
    }
    *(ushort4*)&wtsP[wv][mb] = wb;  // 8-B aligned (mb % 4 == 0)
  }
#pragma unroll
  for (int s = 1; s < 64; s <<= 1) denom += __shfl_xor(denom, s);
  if (lane == 0) redf[wv] = denom;
  __syncthreads();  // wtsP + redf visible to all

  // phase 5: PV. wave wv covers m in [wv*1024, wv*1024+1024)
  const int slot = lane & 7, mg = lane >> 3;
  const int mbase = wv << 10;
  float av[4][4];
#pragma unroll
  for (int r = 0; r < 4; ++r)
#pragma unroll
    for (int c = 0; c < 4; ++c) av[r][c] = 0.f;

#pragma unroll 8
  for (int ii = 0; ii < 128; ++ii) {
    const int m = mbase + (ii << 3) + mg;
    float w0 = bf2f(wtsP[0][m]);
    float w1 = bf2f(wtsP[1][m]);
    float w2 = bf2f(wtsP[2][m]);
    float w3 = bf2f(wtsP[3][m]);
    float4 v = *(const float4*)(Vh + m * HD + (slot << 2));
    av[0][0] += w0 * v.x; av[0][1] += w0 * v.y; av[0][2] += w0 * v.z; av[0][3] += w0 * v.w;
    av[1][0] += w1 * v.x; av[1][1] += w1 * v.y; av[1][2] += w1 * v.z; av[1][3] += w1 * v.w;
    av[2][0] += w2 * v.x; av[2][1] += w2 * v.y; av[2][2] += w2 * v.z; av[2][3] += w2 * v.w;
    av[3][0] += w3 * v.x; av[3][1] += w3 * v.y; av[3][2] += w3 * v.z; av[3][3] += w3 * v.w;
  }
  // reduce over mg (lane bits 3..5)
#pragma unroll
  for (int r = 0; r < 4; ++r)
#pragma unroll
    for (int c = 0; c < 4; ++c) {
      float x = av[r][c];
      x += __shfl_xor(x, 8); x += __shfl_xor(x, 16); x += __shfl_xor(x, 32);
      av[r][c] = x;
    }
  if (mg == 0) {
#pragma unroll
    for (int r = 0; r < 4; ++r)
#pragma unroll
      for (int c = 0; c < 4; ++c)
        pvred[(((wv << 3) + slot) * 4 + r) * 4 + c] = av[r][c];
  }
  __syncthreads();

  if (tid < 128) {
    const int r = tid >> 5, d = tid & 31;
    const int sl = d >> 2, c = d & 3;
    float val = 0.f;
#pragma unroll
    for (int w = 0; w < 4; ++w) val += pvred[(((w << 3) + sl) * 4 + r) * 4 + c];
    val /= redf[r];
    AO[(head * HD + d) * NTOK + n0 + r] = val;  // [C][N] for proj GEMM
  }
}

// ---- kernel 5: GroupNorm stats (32 groups of 8 ch x 4096 = 32768 vals) ----

__global__ __launch_bounds__(256) void gn_stats(const float* __restrict__ O,
                                                float* __restrict__ ST) {
  const int g = blockIdx.x, tid = threadIdx.x;
  const float4* p4 = (const float4*)(O + g * 32768);
  float s = 0.f, ss = 0.f;
  for (int i = tid; i < 8192; i += 256) {
    float4 v = p4[i];
    s += (v.x + v.y) + (v.z + v.w);
    ss += (v.x * v.x + v.y * v.y) + (v.z * v.z + v.w * v.w);
  }
#pragma unroll
  for (int m = 1; m < 64; m <<= 1) {
    s += __shfl_xor(s, m);
    ss += __shfl_xor(ss, m);
  }
  __shared__ float rs[4], rss[4];
  if ((tid & 63) == 0) { rs[tid >> 6] = s; rss[tid >> 6] = ss; }
  __syncthreads();
  if (tid == 0) {
    float S = rs[0] + rs[1] + rs[2] + rs[3];
    float SS = rss[0] + rss[1] + rss[2] + rss[3];
    float mean = S * (1.f / 32768.f);
    float var = SS * (1.f / 32768.f) - mean * mean;
    ST[g * 2] = mean;
    ST[g * 2 + 1] = rsqrtf(var + 1e-6f);
  }
}

// ---- kernel 6: GroupNorm apply (in place on d_out) ------------------------
// Indexes FLOAT4s: total 1048576/4 = 262144 -> grid 1024 x 256.

__global__ __launch_bounds__(256) void gn_apply(float* __restrict__ O,
                                                const float* __restrict__ ST,
                                                const float* __restrict__ gamma,
                                                const float* __restrict__ beta) {
  const int i4 = blockIdx.x * 256 + threadIdx.x;  // float4 index
  const int c = i4 >> 10, g = c >> 3;
  const float a = ST[g * 2 + 1] * gamma[c];
  const float b = beta[c] - ST[g * 2] * a;
  float4 v = *(float4*)(O + (i4 << 2));
  v.x = v.x * a + b; v.y = v.y * a + b; v.z = v.z * a + b; v.w = v.w * a + b;
  *(float4*)(O + (i4 << 2)) = v;
}

// ---- launch ---------------------------------------------------------------

extern "C" void kernel_launch(void* const* d_in, const int* in_sizes, int n_in,
                              void* d_out, int out_size, void* d_ws,
                              size_t ws_size, hipStream_t stream) {
  const float* x = (const float*)d_in[0];       // [256][4096]
  const float* w_qkv = (const float*)d_in[1];   // [768][256]
  const float* w_proj = (const float*)d_in[2];  // [256][256]
  const float* gamma = (const float*)d_in[3];   // [256]
  const float* beta = (const float*)d_in[4];    // [256]
  float* out = (float*)d_out;                   // [256][4096]

  float* Q = (float*)d_ws;          // [8][4096][32]
  float* KT = Q + 1048576;          // [8][32][4096]  (transposed)
  float* V = KT + 1048576;          // [8][4096][32]
  float* AO = V + 1048576;          // [256][4096]
  float* ST = AO + 1048576;         // [32][2]

  gemm_k256<true><<<dim3(64, 12), 256, 0, stream>>>(w_qkv, x, Q, KT, V);
  l2norm_q<<<4096, 256, 0, stream>>>(Q);
  l2norm_kt<<<dim3(16, 8), 256, 0, stream>>>(KT);
  attn_kernel<<<8192, 256, 0, stream>>>(Q, KT, V, AO);
  gemm_k256<false><<<dim3(64, 4), 256, 0, stream>>>(w_proj, AO, out, nullptr, nullptr);
  gn_stats<<<32, 256, 0, stream>>>(out, ST);
  gn_apply<<<1024, 256, 0, stream>>>(out, ST, gamma, beta);
}

// Round 8
// 841.170 us; speedup vs baseline: 2.0613x; 1.3917x over previous
//
#include <hip/hip_runtime.h>

// ---------------------------------------------------------------------------
// LowFreqSparseAttention: qkv 1x1conv -> l2norm(q,k) -> S=QK^T*scale ->
// top-k(k=N/2) mask -> softmax -> PV -> proj 1x1conv -> GroupNorm(32 groups).
// B=1, C=256, H=W=64 -> N=4096, 8 heads, hd=32, k_sel=2048.
//
// R8 (post-mortem R7: absmax 6.28 -- phase 4 used the old m=(i<<6)+lane
// column mapping while kr[] is laid out as kr[(ch<<2)+t] = column
// ch*256+lane*4+t since R6. Weights were scattered to wrong columns; the
// permutation-invariant threshold/denominator masked it until PV. Fix:
// phase 4 indexes m=(g<<8)+cbase+t, weight from kr[(g<<2)+t].)
// Everything else identical to R7:
//  * u8 weights in wtsT[m][4rows], scale cancels in sum(u*v)/sum(u),
//    integer denominator; LDS ~18.9KB total.
//  * early-exit bisection on count==KSEL (exact, tie-free case).
//  * raw fp32 scores in kr, bisection compares float vs unfkey(mid).
// ---------------------------------------------------------------------------

#define NTOK 4096
#define HD 32
#define NHEADS 8
#define KSEL 2048
#define SCALE 0.17677669529663689f   // 32^-0.5  (folded into l2norm_q)
#define LOG2C 7.73937f               // log2(255 / e^0.1767767)

// ---- helpers --------------------------------------------------------------

__device__ __forceinline__ float unfkey(unsigned k) {
  unsigned b = (k & 0x80000000u) ? (k ^ 0x80000000u) : ~k;
  return __uint_as_float(b);
}

// ---- kernel 1/4: GEMM  C[M][4096] = A[M][256] * B[256][4096] --------------
// SCATTER: M=768 -> Q [h][n][d], KT [h][d][n] (transposed!), V [h][n][d].
// else:    M=256 -> plain row-major C0.

template <bool SCATTER>
__global__ __launch_bounds__(256) void gemm_k256(
    const float* __restrict__ A, const float* __restrict__ B,
    float* __restrict__ C0, float* __restrict__ C1, float* __restrict__ C2) {
  __shared__ float Wt[64][17];   // +1 pad: avoid 16-way bank conflict
  __shared__ float Xt[16][64];

  const int tid = threadIdx.x;
  const int tx = tid & 15, ty = tid >> 4;
  const int o0 = blockIdx.y * 64, n0 = blockIdx.x * 64;

  const int wr = tid >> 2, wc = (tid & 3) << 2;   // W-tile 64x16 loader
  const int xr = tid >> 4, xc = (tid & 15) << 2;  // X-tile 16x64 loader

  float4 acc[4];
#pragma unroll
  for (int i = 0; i < 4; ++i) acc[i] = make_float4(0.f, 0.f, 0.f, 0.f);

  for (int k0 = 0; k0 < 256; k0 += 16) {
    float4 wv = *(const float4*)(A + (o0 + wr) * 256 + k0 + wc);
    float4 xv = *(const float4*)(B + (k0 + xr) * 4096 + n0 + xc);
    Wt[wr][wc + 0] = wv.x; Wt[wr][wc + 1] = wv.y;
    Wt[wr][wc + 2] = wv.z; Wt[wr][wc + 3] = wv.w;
    *(float4*)&Xt[xr][xc] = xv;
    __syncthreads();
#pragma unroll
    for (int kk = 0; kk < 16; ++kk) {
      float4 b = *(const float4*)&Xt[kk][tx << 2];
#pragma unroll
      for (int i = 0; i < 4; ++i) {
        float a = Wt[(ty << 2) + i][kk];
        acc[i].x += a * b.x; acc[i].y += a * b.y;
        acc[i].z += a * b.z; acc[i].w += a * b.w;
      }
    }
    __syncthreads();
  }

  if (SCATTER) {
#pragma unroll
    for (int i = 0; i < 4; ++i) {
      int o = o0 + (ty << 2) + i;
      int which = o >> 8, rem = o & 255;
      int h = rem >> 5, d = rem & 31;
      int n = n0 + (tx << 2);
      if (which == 1) {
        // KT[h][d][n..n+3]: contiguous float4
        *(float4*)(C1 + h * (HD * NTOK) + d * NTOK + n) = acc[i];
      } else {
        float* dst = (which == 0) ? C0 : C2;
        int base = h * (NTOK * HD) + d;
        dst[base + (n + 0) * HD] = acc[i].x;
        dst[base + (n + 1) * HD] = acc[i].y;
        dst[base + (n + 2) * HD] = acc[i].z;
        dst[base + (n + 3) * HD] = acc[i].w;
      }
    }
  } else {
#pragma unroll
    for (int i = 0; i < 4; ++i) {
      int o = o0 + (ty << 2) + i;
      *(float4*)(C0 + o * 4096 + n0 + (tx << 2)) = acc[i];
    }
  }
}

// ---- kernel 2a: l2norm Q rows [h][n][32], folds SCALE ---------------------

__global__ __launch_bounds__(256) void l2norm_q(float* __restrict__ Q) {
  const int tid = threadIdx.x;
  const int p = blockIdx.x * 8 + (tid >> 5);  // (head*4096+n) row index
  const int d = tid & 31;
  const int idx = p * HD + d;
  float v = Q[idx];
  float ss = v * v;
#pragma unroll
  for (int m = 16; m >= 1; m >>= 1) ss += __shfl_xor(ss, m, 32);
  float nrm = sqrtf(ss);
  Q[idx] = v * SCALE / fmaxf(nrm, 1e-12f);
}

// ---- kernel 2b: l2norm KT columns (norm over d at fixed n) ----------------

__global__ __launch_bounds__(256) void l2norm_kt(float* __restrict__ KT) {
  const int n = blockIdx.x * 256 + threadIdx.x;
  float* P = KT + blockIdx.y * (HD * NTOK) + n;
  float v[HD];
  float ss = 0.f;
#pragma unroll
  for (int d = 0; d < HD; ++d) {
    v[d] = P[d * NTOK];          // coalesced across lanes
    ss += v[d] * v[d];
  }
  float inv = 1.f / fmaxf(sqrtf(ss), 1e-12f);
#pragma unroll
  for (int d = 0; d < HD; ++d) P[d * NTOK] = v[d] * inv;
}

// ---- kernel 3: fused attention (4 rows per block, wave wv owns row wv) ----
// phase2: wave-per-row fp32 scores from KT, dwordx4-coalesced -> kr[64]
//         kr[(ch<<2)+t] = score of column ch*256 + lane*4 + t
// phase3: ballot-bisection with exact early exit (count==KSEL)
// phase4: u8 weights u=rint(exp2(fma(s,1.4427,LOG2C))) -> wtsT[m][row],
//         integer denominators; SAME column mapping as kr (R7's bug)
// phase5: PV accumulate u*v (V fp32), cross-lane reduce, write AO[c][n]

__global__ __launch_bounds__(256) void attn_kernel(
    const float* __restrict__ Q, const float* __restrict__ KT,
    const float* __restrict__ V, float* __restrict__ AO) {
  __shared__ __align__(16) unsigned char wtsT[NTOK][4];   // 16 KB, [m][row]
  __shared__ float qs[128];
  __shared__ float pvred[4 * 8 * 4 * 4];                  // 2 KB
  __shared__ float redf[4];                               // float(sum u)

  const int tid = threadIdx.x;
  const int wv = tid >> 6, lane = tid & 63;
  const int head = blockIdx.x & 7;          // head == blockIdx%8 -> XCD-pinned
  const int n0 = (blockIdx.x >> 3) << 2;

  const float* Qh = Q + head * (NTOK * HD);
  const float* KTh = KT + head * (HD * NTOK);
  const float* Vh = V + head * (NTOK * HD);

  // phase 1: stage the block's 4 q rows (already *SCALE from l2norm_q)
  if (tid < 128) qs[tid] = Qh[n0 * HD + tid];
  __syncthreads();

  float qv[HD];
#pragma unroll
  for (int d = 0; d < HD; ++d) qv[d] = qs[wv * HD + d];

  // phase 2: wave wv computes row wv's scores. kr[ch*4+t] holds column
  // ch*256 + lane*4 + t. FULL unroll keeps kr register-resident (dynamic
  // indexing demotes it to scratch -- R4). No barriers (R6).
  float kr[64];
  const int cbase = lane << 2;
#pragma unroll
  for (int ch = 0; ch < 16; ++ch) {
    const float* kp = KTh + (ch << 8) + cbase;
    float a0 = 0.f, a1 = 0.f, a2 = 0.f, a3 = 0.f;
#pragma unroll
    for (int d = 0; d < HD; ++d) {
      float4 kv = *(const float4*)(kp + d * NTOK);
      a0 += qv[d] * kv.x; a1 += qv[d] * kv.y;
      a2 += qv[d] * kv.z; a3 += qv[d] * kv.w;
    }
    kr[(ch << 2) + 0] = a0;
    kr[(ch << 2) + 1] = a1;
    kr[(ch << 2) + 2] = a2;
    kr[(ch << 2) + 3] = a3;
  }

  // phase 3: bisection on the uint key grid, comparing in float.
  // count(f >= unfkey(mid)) is non-increasing in mid. Early exit when the
  // count hits KSEL exactly (tie-free boundary: kept set == reference's).
  unsigned lo = 0u, hi = 0xFFFFFFFFu;
  for (int it = 0; it < 32; ++it) {
    unsigned mid = (unsigned)((((unsigned long long)lo) + hi + 1ull) >> 1);
    float midf = unfkey(mid);
    int c = 0;
#pragma unroll
    for (int i = 0; i < 64; ++i)
      c += __popcll(__ballot(kr[i] >= midf));
    if (c == KSEL) { lo = mid; break; }
    if (c > KSEL) lo = mid; else hi = mid - 1;
  }
  const float tf = unfkey(lo);

  // phase 4: u8 weights + integer denominator for row wv.
  // COLUMN MAPPING MATCHES kr: m = g*256 + lane*4 + t <-> kr[(g<<2)+t].
  // u = rint(exp(s) * 255/e^smax) in [179,255] for kept, 0 for masked.
  unsigned idenom = 0;
#pragma unroll
  for (int g = 0; g < 16; ++g) {
#pragma unroll
    for (int t = 0; t < 4; ++t) {
      const int m = (g << 8) + cbase + t;
      float f = kr[(g << 2) + t];
      float e = exp2f(__builtin_fmaf(f, 1.44269504f, LOG2C));
      unsigned u = (f >= tf) ? (unsigned)rintf(e) : 0u;
      wtsT[m][wv] = (unsigned char)u;   // ds_write_b8; rows disjoint bytes
      idenom += u;
    }
  }
#pragma unroll
  for (int s = 1; s < 64; s <<= 1) idenom += __shfl_xor(idenom, s);
  if (lane == 0) redf[wv] = (float)idenom;
  __syncthreads();  // wtsT + redf visible to all

  // phase 5: PV with integer weights. wave wv covers m in [wv*1024, +1024).
  const int slot = lane & 7, mg = lane >> 3;
  const int mbase = wv << 10;
  float av[4][4];
#pragma unroll
  for (int r = 0; r < 4; ++r)
#pragma unroll
    for (int c = 0; c < 4; ++c) av[r][c] = 0.f;

#pragma unroll 8
  for (int ii = 0; ii < 128; ++ii) {
    const int m = mbase + (ii << 3) + mg;
    unsigned wq = *(const unsigned*)&wtsT[m][0];   // one b32: rows 0..3
    float4 v = *(const float4*)(Vh + m * HD + (slot << 2));
    float w0 = (float)(wq & 0xFFu);          // v_cvt_f32_ubyte0
    float w1 = (float)((wq >> 8) & 0xFFu);   // v_cvt_f32_ubyte1
    float w2 = (float)((wq >> 16) & 0xFFu);  // v_cvt_f32_ubyte2
    float w3 = (float)(wq >> 24);            // v_cvt_f32_ubyte3
    av[0][0] += w0 * v.x; av[0][1] += w0 * v.y; av[0][2] += w0 * v.z; av[0][3] += w0 * v.w;
    av[1][0] += w1 * v.x; av[1][1] += w1 * v.y; av[1][2] += w1 * v.z; av[1][3] += w1 * v.w;
    av[2][0] += w2 * v.x; av[2][1] += w2 * v.y; av[2][2] += w2 * v.z; av[2][3] += w2 * v.w;
    av[3][0] += w3 * v.x; av[3][1] += w3 * v.y; av[3][2] += w3 * v.z; av[3][3] += w3 * v.w;
  }
  // reduce over mg (lane bits 3..5)
#pragma unroll
  for (int r = 0; r < 4; ++r)
#pragma unroll
    for (int c = 0; c < 4; ++c) {
      float x = av[r][c];
      x += __shfl_xor(x, 8); x += __shfl_xor(x, 16); x += __shfl_xor(x, 32);
      av[r][c] = x;
    }
  if (mg == 0) {
#pragma unroll
    for (int r = 0; r < 4; ++r)
#pragma unroll
      for (int c = 0; c < 4; ++c)
        pvred[(((wv << 3) + slot) * 4 + r) * 4 + c] = av[r][c];
  }
  __syncthreads();

  if (tid < 128) {
    const int r = tid >> 5, d = tid & 31;
    const int sl = d >> 2, c = d & 3;
    float val = 0.f;
#pragma unroll
    for (int w = 0; w < 4; ++w) val += pvred[(((w << 3) + sl) * 4 + r) * 4 + c];
    val /= redf[r];
    AO[(head * HD + d) * NTOK + n0 + r] = val;  // [C][N] for proj GEMM
  }
}

// ---- kernel 5: GroupNorm stats (32 groups of 8 ch x 4096 = 32768 vals) ----

__global__ __launch_bounds__(256) void gn_stats(const float* __restrict__ O,
                                                float* __restrict__ ST) {
  const int g = blockIdx.x, tid = threadIdx.x;
  const float4* p4 = (const float4*)(O + g * 32768);
  float s = 0.f, ss = 0.f;
  for (int i = tid; i < 8192; i += 256) {
    float4 v = p4[i];
    s += (v.x + v.y) + (v.z + v.w);
    ss += (v.x * v.x + v.y * v.y) + (v.z * v.z + v.w * v.w);
  }
#pragma unroll
  for (int m = 1; m < 64; m <<= 1) {
    s += __shfl_xor(s, m);
    ss += __shfl_xor(ss, m);
  }
  __shared__ float rs[4], rss[4];
  if ((tid & 63) == 0) { rs[tid >> 6] = s; rss[tid >> 6] = ss; }
  __syncthreads();
  if (tid == 0) {
    float S = rs[0] + rs[1] + rs[2] + rs[3];
    float SS = rss[0] + rss[1] + rss[2] + rss[3];
    float mean = S * (1.f / 32768.f);
    float var = SS * (1.f / 32768.f) - mean * mean;
    ST[g * 2] = mean;
    ST[g * 2 + 1] = rsqrtf(var + 1e-6f);
  }
}

// ---- kernel 6: GroupNorm apply (in place on d_out) ------------------------
// Indexes FLOAT4s: total 1048576/4 = 262144 -> grid 1024 x 256.

__global__ __launch_bounds__(256) void gn_apply(float* __restrict__ O,
                                                const float* __restrict__ ST,
                                                const float* __restrict__ gamma,
                                                const float* __restrict__ beta) {
  const int i4 = blockIdx.x * 256 + threadIdx.x;  // float4 index
  const int c = i4 >> 10, g = c >> 3;
  const float a = ST[g * 2 + 1] * gamma[c];
  const float b = beta[c] - ST[g * 2] * a;
  float4 v = *(float4*)(O + (i4 << 2));
  v.x = v.x * a + b; v.y = v.y * a + b; v.z = v.z * a + b; v.w = v.w * a + b;
  *(float4*)(O + (i4 << 2)) = v;
}

// ---- launch ---------------------------------------------------------------

extern "C" void kernel_launch(void* const* d_in, const int* in_sizes, int n_in,
                              void* d_out, int out_size, void* d_ws,
                              size_t ws_size, hipStream_t stream) {
  const float* x = (const float*)d_in[0];       // [256][4096]
  const float* w_qkv = (const float*)d_in[1];   // [768][256]
  const float* w_proj = (const float*)d_in[2];  // [256][256]
  const float* gamma = (const float*)d_in[3];   // [256]
  const float* beta = (const float*)d_in[4];    // [256]
  float* out = (float*)d_out;                   // [256][4096]

  float* Q = (float*)d_ws;          // [8][4096][32]
  float* KT = Q + 1048576;          // [8][32][4096]  (transposed)
  float* V = KT + 1048576;          // [8][4096][32]
  float* AO = V + 1048576;          // [256][4096]
  float* ST = AO + 1048576;         // [32][2]

  gemm_k256<true><<<dim3(64, 12), 256, 0, stream>>>(w_qkv, x, Q, KT, V);
  l2norm_q<<<4096, 256, 0, stream>>>(Q);
  l2norm_kt<<<dim3(16, 8), 256, 0, stream>>>(KT);
  attn_kernel<<<8192, 256, 0, stream>>>(Q, KT, V, AO);
  gemm_k256<false><<<dim3(64, 4), 256, 0, stream>>>(w_proj, AO, out, nullptr, nullptr);
  gn_stats<<<32, 256, 0, stream>>>(out, ST);
  gn_apply<<<1024, 256, 0, stream>>>(out, ST, gamma, beta);
}